// Round 8
// baseline (189.923 us; speedup 1.0000x reference)
//
#include <hip/hip_runtime.h>
#include <hip/hip_bf16.h>
#include <hip/hip_fp16.h>

// out[e] = relu(z_s[row[e]]@W1_top + z_c[col[e]]@W1_bot + b1) @ W2 + b2
// u_s = z_s@W1_top + b1 (f16), u_c = z_c@W1_bot (f16) in ws.
// Edges counting-sorted by row>>7 (782 buckets of 128 rows).
// k4 runs TWICE over feature halves (64 feats each): per pass the gathered
// u_c half-table is 2.55 MB -> L2-resident per XCD (vs 5.1 MB > 4 MB L2).
// relu is per-feature and the W2 dot splits over features, so pass partials
// sum exactly: pass0 writes out[e], pass1 does out[e] += partial + b2.

typedef _Float16 half2v __attribute__((ext_vector_type(2)));
typedef _Float16 half8v __attribute__((ext_vector_type(8)));
typedef __fp16   fp16x2 __attribute__((ext_vector_type(2)));
typedef float    float4v __attribute__((ext_vector_type(4)));

#define NB 1024         // bins (buckets 0..781 used)
#define EH 8448         // edges per hist block (33 x 256)
#define EBLK_S 4096     // edges per scatter block
#define TPB 4           // M-tiles (64 rows) per gemm block

// ---- K1: blocks 0-7 W1->Wt f16 transpose; 8: W2->f16; 9+: hist (atomic) ----
__global__ __launch_bounds__(256) void k1_conv_hist(
    const float* __restrict__ W1, const float* __restrict__ W2,
    const int* __restrict__ row,
    _Float16* __restrict__ Wt, _Float16* __restrict__ w2h,
    unsigned* __restrict__ hist, int E)
{
    int b = blockIdx.x, t = threadIdx.x;
    if (b >= 9) {
        __shared__ unsigned h[NB];
        #pragma unroll
        for (int i = 0; i < 4; ++i) h[t + i * 256] = 0;
        __syncthreads();
        long b0 = (long)(b - 9) * EH;
        for (int i = 0; i < 33; ++i) {
            long e = b0 + i * 256 + t;
            if (e < E) atomicAdd(&h[row[e] >> 7], 1u);
        }
        __syncthreads();
        #pragma unroll
        for (int i = 0; i < 4; ++i) {
            unsigned v = h[t + i * 256];
            if (v) atomicAdd(&hist[t + i * 256], v);
        }
        return;
    }
    if (b == 8) { if (t < 128) w2h[t] = (_Float16)W2[t]; return; }
    __shared__ _Float16 lds[32][136];
    int h2 = b >> 2, n0 = (b & 3) * 32;
    for (int i = 0; i < 16; ++i) {
        int idx = i * 256 + t;
        int k = idx >> 5, nn = idx & 31;
        lds[nn][k] = (_Float16)W1[(h2 * 128 + k) * 128 + n0 + nn];
    }
    __syncthreads();
    for (int j = 0; j < 2; ++j) {
        int idx = j * 256 + t;
        int nn = idx >> 4, kc = idx & 15;
        half8v v;
        #pragma unroll
        for (int q = 0; q < 8; ++q) v[q] = lds[nn][kc * 8 + q];
        *(half8v*)&Wt[((h2 * 128 + n0 + nn) * 128) + kc * 8] = v;
    }
}

// ---- K2: exclusive scan of 1024 bins ----
__global__ __launch_bounds__(1024) void k2_scan(const unsigned* __restrict__ hist,
                                                unsigned* __restrict__ bucketStart,
                                                unsigned* __restrict__ cursor, int E)
{
    __shared__ unsigned s[NB];
    int t = threadIdx.x;
    unsigned v = hist[t];
    s[t] = v;
    __syncthreads();
    for (int d = 1; d < NB; d <<= 1) {
        unsigned x = (t >= d) ? s[t - d] : 0u;
        __syncthreads();
        s[t] += x;
        __syncthreads();
    }
    unsigned excl = s[t] - v;
    bucketStart[t] = excl;
    cursor[t] = excl;
    if (t == 0) bucketStart[NB] = (unsigned)E;
}

// ---- K3: blocks [0,nbs_s) scatter; rest = gemm, 4 tiles/block, prefetch ----
__global__ __launch_bounds__(256, 3) void k3_scatter_gemm(
    const int* __restrict__ row, const int* __restrict__ col,
    unsigned* __restrict__ cursor, uint2* __restrict__ perm, int E, int nbs_s,
    const float* __restrict__ Zs, const float* __restrict__ Zc,
    const _Float16* __restrict__ Wt, const float* __restrict__ b1,
    _Float16* __restrict__ Us, _Float16* __restrict__ Uc,
    int Ms, int Mc, int nbsg)
{
    __shared__ __align__(16) unsigned smem[8192];   // 32 KB, unioned
    const int t = threadIdx.x;
    if (blockIdx.x < (unsigned)nbs_s) {
        // ---------------- scatter ----------------
        unsigned* h    = smem;          // [NB]
        unsigned* base = smem + NB;     // [NB]
        #pragma unroll
        for (int i = 0; i < 4; ++i) h[t + i * 256] = 0;
        __syncthreads();
        long b0 = (long)blockIdx.x * EBLK_S;
        int sk[16], rr[16], cc[16];
        #pragma unroll
        for (int i = 0; i < 16; ++i) {
            long e = b0 + i * 256 + t;
            if (e < E) {
                rr[i] = row[e]; cc[i] = col[e];
                sk[i] = rr[i] >> 7;
                atomicAdd(&h[sk[i]], 1u);
            } else sk[i] = -1;
        }
        __syncthreads();
        #pragma unroll
        for (int i = 0; i < 4; ++i) {
            unsigned hv = h[t + i * 256];
            if (hv) base[t + i * 256] = atomicAdd(&cursor[t + i * 256], hv);
        }
        __syncthreads();
        #pragma unroll
        for (int i = 0; i < 4; ++i) h[t + i * 256] = 0;
        __syncthreads();
        #pragma unroll
        for (int i = 0; i < 16; ++i) {
            if (sk[i] >= 0) {
                unsigned off = atomicAdd(&h[sk[i]], 1u);
                unsigned pos = base[sk[i]] + off;
                long e = b0 + i * 256 + t;
                perm[pos] = make_uint2(((unsigned)(rr[i] & 127) << 15) | (unsigned)cc[i],
                                       (unsigned)e);
            }
        }
        return;
    }
    // ---------------- GEMM: TPB tiles of 64 rows ----------------
    uint4* ldsW = (uint4*)smem;
    int gid = blockIdx.x - nbs_s;

    const float* Z; _Float16* U; const _Float16* W; int M, tbase, addB;
    if (gid < nbsg) { Z = Zs; U = Us; M = Ms; W = Wt;         addB = 1; tbase = gid * TPB; }
    else { gid -= nbsg; Z = Zc; U = Uc; M = Mc; W = Wt + 16384; addB = 0; tbase = gid * TPB; }

    const uint4* Wv = (const uint4*)W;
    #pragma unroll
    for (int i = 0; i < 8; ++i) {
        int j = i * 256 + t;
        int n = j >> 4, ch = j & 15;
        ldsW[n * 16 + (ch ^ ((n >> 3) & 7))] = Wv[j];
    }
    __syncthreads();

    const int wave = t >> 6, lane = t & 63, quad = lane >> 4, l16 = lane & 15;

    float bv[8];
    if (addB) {
        const float4v* pb1 = (const float4v*)(b1 + l16 * 8);
        float4v x0 = pb1[0], x1 = pb1[1];
        bv[0]=x0[0]; bv[1]=x0[1]; bv[2]=x0[2]; bv[3]=x0[3];
        bv[4]=x1[0]; bv[5]=x1[1]; bv[6]=x1[2]; bv[7]=x1[3];
    } else {
        #pragma unroll
        for (int i = 0; i < 8; ++i) bv[i] = 0.0f;
    }

    float4v buf[2][8];
    #define LOADZ(dst, tile) do {                                              \
        int mrow_ = (tile) * 64 + wave * 16 + l16;                             \
        int mload_ = mrow_ < M ? mrow_ : M - 1;                                \
        const float4v* p_ = (const float4v*)(Z + (long)mload_ * 128);          \
        _Pragma("unroll")                                                      \
        for (int c_ = 0; c_ < 4; ++c_) {                                       \
            (dst)[2*c_]   = p_[c_*8 + quad*2];                                 \
            (dst)[2*c_+1] = p_[c_*8 + quad*2 + 1];                             \
        }                                                                      \
    } while (0)

    LOADZ(buf[0], tbase);
    #pragma unroll
    for (int tt = 0; tt < TPB; ++tt) {
        const float4v* cur = buf[tt & 1];
        if (tt + 1 < TPB) LOADZ(buf[(tt + 1) & 1], tbase + tt + 1);

        float4v acc[8];
        #pragma unroll
        for (int nt = 0; nt < 8; ++nt) acc[nt] = (float4v)(0.0f);

        #pragma unroll
        for (int c = 0; c < 4; ++c) {
            float4v a0 = cur[2*c], a1 = cur[2*c+1];
            fp16x2 p[4];
            p[0] = __builtin_amdgcn_cvt_pkrtz(a0[0], a0[1]);
            p[1] = __builtin_amdgcn_cvt_pkrtz(a0[2], a0[3]);
            p[2] = __builtin_amdgcn_cvt_pkrtz(a1[0], a1[1]);
            p[3] = __builtin_amdgcn_cvt_pkrtz(a1[2], a1[3]);
            half8v af;
            __builtin_memcpy(&af, &p[0], 16);
            const int ch = c * 4 + quad;
            #pragma unroll
            for (int nt = 0; nt < 8; ++nt) {
                const int n = l16 * 8 + nt;
                const half8v* pb = (const half8v*)&ldsW[n * 16 + (ch ^ (l16 & 7))];
                acc[nt] = __builtin_amdgcn_mfma_f32_16x16x32_f16(af, *pb, acc[nt], 0, 0, 0);
            }
        }

        const int rbase = (tbase + tt) * 64 + wave * 16 + quad * 4;
        #pragma unroll
        for (int r = 0; r < 4; ++r) {
            int rr2 = rbase + r;
            if (rr2 < M) {
                half8v o;
                #pragma unroll
                for (int nt = 0; nt < 8; ++nt) o[nt] = (_Float16)(acc[nt][r] + bv[nt]);
                *(half8v*)&U[(long)rr2 * 128 + l16 * 8] = o;
            }
        }
    }
    #undef LOADZ
}

// ---- K4: one feature-half pass. 2 WGs/bucket, 16KB us window in LDS,
//          4 lanes/edge (64 edges in flight/WG), uc half-table L2-resident ----
__global__ __launch_bounds__(256) void k4_edge(
    const uint2* __restrict__ perm, const unsigned* __restrict__ bucketStart,
    const _Float16* __restrict__ us, const _Float16* __restrict__ uc,
    const _Float16* __restrict__ w2h, const float* __restrict__ b2,
    float* __restrict__ out, int Ms, int fh, int finalPass)
{
    __shared__ uint4 lu[1024];          // 128 rows x 8 chunks (16 KB), swizzled
    const int t = threadIdx.x;
    const int b = blockIdx.x >> 1, half = blockIdx.x & 1;
    const int r0 = b << 7;
    const uint4* usv = (const uint4*)us;
    #pragma unroll
    for (int i = 0; i < 4; ++i) {
        int j = t + i * 256;            // 1024 uint4
        int rl = j >> 3, ch = j & 7;
        int r = r0 + rl; if (r >= Ms) r = Ms - 1;
        lu[rl * 8 + (ch ^ (rl & 7))] = usv[(long)r * 16 + fh * 8 + ch];
    }
    const int sub = t & 3;
    const uint4* pw = ((const uint4*)(w2h + fh * 64)) + sub * 2;
    uint4 w0 = pw[0], w1 = pw[1];
    half2v W[8];
    *(uint4*)&W[0] = w0; *(uint4*)&W[4] = w1;
    const float b2v = b2[0];
    const half2v zero = {(_Float16)0, (_Float16)0};
    unsigned s0b = bucketStart[b], s1b = bucketStart[b + 1];
    __syncthreads();

    unsigned cntAll = s1b - s0b;
    if (cntAll == 0) return;
    unsigned hc = (cntAll + 1) >> 1;
    unsigned s0 = s0b + half * hc;
    unsigned s1 = s0 + hc; if (s1 > s1b) s1 = s1b;
    if (s0 >= s1) return;
    const unsigned cnt = s1 - s0;
    const uint4* ucv = (const uint4*)uc;

    // 2-deep perm / 1-deep uc software pipeline (clamped prefetch indices)
    unsigned k = t >> 2;                                   // slot 0..63, stride 64
    uint2 pcA = perm[s0 + (k        < cnt ? k        : 0u)];
    uint2 pcB = perm[s0 + (k + 64u  < cnt ? k + 64u  : 0u)];
    uint4 U0, U1;
    {
        const uint4* pb = ucv + (long)(pcA.x & 32767u) * 16 + fh * 8 + sub * 2;
        U0 = pb[0]; U1 = pb[1];
    }
    for (; k < cnt; k += 64u) {
        uint2 pcC = perm[s0 + (k + 128u < cnt ? k + 128u : 0u)];
        uint4 V0, V1;
        {
            const uint4* pb = ucv + (long)(pcB.x & 32767u) * 16 + fh * 8 + sub * 2;
            V0 = pb[0]; V1 = pb[1];
        }
        unsigned rloc = pcA.x >> 15;
        int m = rloc & 7;
        uint4 a0 = lu[rloc * 8 + ((sub * 2) ^ m)];
        uint4 a1 = lu[rloc * 8 + ((sub * 2 + 1) ^ m)];

        half2v A[8], B[8];
        *(uint4*)&A[0] = a0; *(uint4*)&A[4] = a1;
        *(uint4*)&B[0] = U0; *(uint4*)&B[4] = U1;

        float s = 0.0f;
        #pragma unroll
        for (int i = 0; i < 8; ++i) {
            half2v h = A[i] + B[i];                   // v_pk_add_f16
            h = __builtin_elementwise_max(h, zero);   // v_pk_max_f16
            s += (float)h[0] * (float)W[i][0];
            s += (float)h[1] * (float)W[i][1];
        }
        s += __shfl_xor(s, 1);
        s += __shfl_xor(s, 2);
        if (sub == 0) {
            if (finalPass) out[pcA.y] += s + b2v;     // pass1: accumulate + bias
            else           out[pcA.y]  = s;           // pass0: init with partial
        }
        pcA = pcB; pcB = pcC; U0 = V0; U1 = V1;
    }
}

extern "C" void kernel_launch(void* const* d_in, const int* in_sizes, int n_in,
                              void* d_out, int out_size, void* d_ws, size_t ws_size,
                              hipStream_t stream) {
    const float* zs  = (const float*)d_in[0];
    const float* zc  = (const float*)d_in[1];
    const int*   row = (const int*)d_in[2];
    const int*   col = (const int*)d_in[3];
    const float* W1  = (const float*)d_in[4];
    const float* b1  = (const float*)d_in[5];
    const float* W2  = (const float*)d_in[6];
    const float* b2  = (const float*)d_in[7];
    float* out = (float*)d_out;

    const int Ms = in_sizes[0] / 128;   // 100000
    const int Mc = in_sizes[1] / 128;   // 20000
    const int E  = in_sizes[2];         // 1000000

    char* w = (char*)d_ws;
    _Float16* Wt     = (_Float16*)(w);                  //      0 .. 65536
    _Float16* w2h    = (_Float16*)(w + 65536);          //  256 B
    unsigned* hist   = (unsigned*)(w + 66560);          //  4096 B
    unsigned* bstart = (unsigned*)(w + 70656);          //  (NB+1)*4 = 4100 B
    unsigned* cursor = (unsigned*)(w + 75776);          //  4096 B
    _Float16* us     = (_Float16*)(w + 81920);          //  Ms*256 B
    _Float16* uc     = (_Float16*)(w + 81920 + (size_t)Ms * 256);
    uint2*    perm   = (uint2*)(w + 81920 + (size_t)(Ms + Mc) * 256);  // E*8 B

    const int nbs = (Ms + 63) / 64, nbc = (Mc + 63) / 64;      // 1563, 313
    const int nbsg = (nbs + TPB - 1) / TPB;                    // 391
    const int nbcg = (nbc + TPB - 1) / TPB;                    // 79
    const int nbh = (E + EH - 1) / EH;                         // 119
    const int nbss = (E + EBLK_S - 1) / EBLK_S;                // 245
    const int nbuckets = (Ms + 127) >> 7;                      // 782

    hipMemsetAsync(hist, 0, NB * 4, stream);
    k1_conv_hist<<<9 + nbh, 256, 0, stream>>>(W1, W2, row, Wt, w2h, hist, E);
    k2_scan<<<1, 1024, 0, stream>>>(hist, bstart, cursor, E);
    k3_scatter_gemm<<<nbss + nbsg + nbcg, 256, 0, stream>>>(row, col, cursor, perm, E, nbss,
                                                            zs, zc, Wt, b1, us, uc, Ms, Mc, nbsg);
    k4_edge<<<2 * nbuckets, 256, 0, stream>>>(perm, bstart, us, uc, w2h, b2, out, Ms, 0, 0);
    k4_edge<<<2 * nbuckets, 256, 0, stream>>>(perm, bstart, us, uc, w2h, b2, out, Ms, 1, 1);
}